// Round 4
// baseline (412.999 us; speedup 1.0000x reference)
//
#include <hip/hip_runtime.h>
#include <math.h>

#define NENTITY 200000
#define HIDDEN 256
#define NEG 1024
#define NBATCH 256
#define GAMMA_F 12.0f
#define BM 32          // rows per tile
#define NTILES 8       // tiles per block (fallback path)
#define NBLK 1024      // (NBATCH*NEG)/(BM*NTILES)
#define CHUNK 128      // negs per score2 block

typedef short v8s __attribute__((ext_vector_type(8)));
typedef float v4f __attribute__((ext_vector_type(4)));
typedef unsigned int u32;

// raw barrier: wait LDS ops only, do NOT drain vmcnt (keeps prefetch in flight)
#define LDS_BARRIER() asm volatile("s_waitcnt lgkmcnt(0)\n\ts_barrier" ::: "memory")

// fp32 -> bf16 round-to-nearest-even
__device__ __forceinline__ short f2bf(float x) {
    u32 u = __float_as_uint(x);
    u = (u + 0x7fffu + ((u >> 16) & 1u)) >> 16;
    return (short)u;
}

// pack 8 fp32 -> v8s bf16 (round-half-up + v_perm byte-pack, 12 VALU)
__device__ __forceinline__ u32 rhu(float f) { return __float_as_uint(f) + 0x8000u; }
__device__ __forceinline__ v8s pack8(const float4& x0, const float4& x1) {
    int4 fr;
    fr.x = __builtin_amdgcn_perm(rhu(x0.y), rhu(x0.x), 0x07060302u);
    fr.y = __builtin_amdgcn_perm(rhu(x0.w), rhu(x0.z), 0x07060302u);
    fr.z = __builtin_amdgcn_perm(rhu(x1.y), rhu(x1.x), 0x07060302u);
    fr.w = __builtin_amdgcn_perm(rhu(x1.w), rhu(x1.z), 0x07060302u);
    return __builtin_bit_cast(v8s, fr);
}

// One block per batch row b: h_n[b,:], rel_part[b,:] in fp32; convert W1 row b -> bf16.
__global__ __launch_bounds__(256) void prep_kernel(
    const int* __restrict__ head, const int* __restrict__ relation,
    const float* __restrict__ entity_emb, const float* __restrict__ relation_emb,
    const float* __restrict__ W_fc, const float* __restrict__ b_fc,
    short* __restrict__ W1bf, float* __restrict__ h_n, float* __restrict__ rel_part)
{
    const int b = blockIdx.x;
    const int t = threadIdx.x;

    W1bf[b * HIDDEN + t] = f2bf(W_fc[(size_t)b * 2 * HIDDEN + t]);

    __shared__ float xh[2 * HIDDEN];
    __shared__ float xt[HIDDEN];
    __shared__ float red[256];

    const int hidx = head[b];
    const int r = relation[b];
    xh[t]          = entity_emb[(size_t)hidx * HIDDEN + t];
    xh[HIDDEN + t] = relation_emb[(size_t)r * 2 * HIDDEN + t];
    xt[t]          = relation_emb[(size_t)r * 2 * HIDDEN + HIDDEN + t];
    __syncthreads();

    const float4* wrow = reinterpret_cast<const float4*>(W_fc + (size_t)t * 2 * HIDDEN);
    float hf = b_fc[t];
    float rp = b_fc[t];
    #pragma unroll 4
    for (int kk = 0; kk < HIDDEN / 4; ++kk) {
        float4 w = wrow[kk];
        hf += xh[4*kk+0]*w.x + xh[4*kk+1]*w.y + xh[4*kk+2]*w.z + xh[4*kk+3]*w.w;
    }
    #pragma unroll 4
    for (int kk = 0; kk < HIDDEN / 4; ++kk) {
        float4 w = wrow[HIDDEN/4 + kk];
        hf += xh[HIDDEN+4*kk+0]*w.x + xh[HIDDEN+4*kk+1]*w.y + xh[HIDDEN+4*kk+2]*w.z + xh[HIDDEN+4*kk+3]*w.w;
        rp += xt[4*kk+0]*w.x + xt[4*kk+1]*w.y + xt[4*kk+2]*w.z + xt[4*kk+3]*w.w;
    }
    rel_part[b * HIDDEN + t] = rp;

    red[t] = hf * hf;
    __syncthreads();
    for (int s = 128; s > 0; s >>= 1) {
        if (t < s) red[t] += red[t + s];
        __syncthreads();
    }
    const float norm = sqrtf(red[0]);
    h_n[b * HIDDEN + t] = hf / fmaxf(norm, 1e-12f);
}

// ---------------------------------------------------------------------------
// R4 NEW PATH, kernel A: P[e,:] = entity_emb[e,:] @ W1^T, bf16, for ALL
// 200000 entities. CONTIGUOUS streaming (no gather): 200 MB read + 100 MB
// write at the 6.3 TB/s streaming rate ~= 50 us; 26 GFLOP MFMA hides under
// it. Single 32-row tile per block; staging/K-loop cloned from the proven
// score structure (reg-stage -> XOR-swizzled LDS -> ds_read_b128 -> MFMA).
// ---------------------------------------------------------------------------
__global__ __launch_bounds__(256, 2) void proj_kernel(
    const float* __restrict__ entity_emb, const short* __restrict__ W1bf,
    short* __restrict__ P)
{
    __shared__ __align__(16) float Asf[BM * HIDDEN];   // 32 KiB

    const int t = threadIdx.x;
    const int w = t >> 6;
    const int l = t & 63;
    const int c = t & 15;
    const int g = (t >> 4) & 3;
    const int R0 = blockIdx.x * BM;

    // preload this wave's B fragments: cols 64w..64w+63, full K
    v8s Bf[4][8];
    #pragma unroll
    for (int ntl = 0; ntl < 4; ++ntl) {
        const short* bsrc = W1bf + (size_t)(64 * w + ntl * 16 + c) * HIDDEN + g * 8;
        #pragma unroll
        for (int kt = 0; kt < 8; ++kt)
            Bf[ntl][kt] = *reinterpret_cast<const v8s*>(bsrc + kt * 32);
    }
    #pragma unroll
    for (int ntl = 0; ntl < 4; ++ntl)
        #pragma unroll
        for (int kt = 0; kt < 8; ++kt)
            asm volatile("" : "+v"(Bf[ntl][kt]));

    // stage 8 contiguous rows per wave (coalesced 1 KiB per instruction)
    v4f st[8];
    #pragma unroll
    for (int i = 0; i < 8; ++i) {
        const int r = w * 8 + i;
        st[i] = *reinterpret_cast<const v4f*>(
            entity_emb + (size_t)(R0 + r) * HIDDEN + (l << 2));
    }
    __builtin_amdgcn_sched_barrier(0);
    #pragma unroll
    for (int i = 0; i < 8; ++i) {
        const int r = w * 8 + i;
        *reinterpret_cast<v4f*>(&Asf[r * HIDDEN + ((l ^ (r & 7)) << 2)]) = st[i];
    }
    LDS_BARRIER();

    v4f acc[2][4];
    #pragma unroll
    for (int mt = 0; mt < 2; ++mt)
        #pragma unroll
        for (int ntl = 0; ntl < 4; ++ntl)
            acc[mt][ntl] = v4f{0.f, 0.f, 0.f, 0.f};

    const float* a0base = &Asf[c * HIDDEN];
    const float* a1base = &Asf[(16 + c) * HIDDEN];
    const int swz = c & 7;

    #pragma unroll
    for (int kt = 0; kt < 8; ++kt) {
        const int u0 = kt * 8 + g * 2;
        float4 x0 = *reinterpret_cast<const float4*>(a0base + (((u0    ) ^ swz) << 2));
        float4 x1 = *reinterpret_cast<const float4*>(a0base + (((u0 + 1) ^ swz) << 2));
        float4 y0 = *reinterpret_cast<const float4*>(a1base + (((u0    ) ^ swz) << 2));
        float4 y1 = *reinterpret_cast<const float4*>(a1base + (((u0 + 1) ^ swz) << 2));
        v8s a0 = pack8(x0, x1);
        v8s a1 = pack8(y0, y1);
        #pragma unroll
        for (int ntl = 0; ntl < 4; ++ntl) {
            acc[0][ntl] = __builtin_amdgcn_mfma_f32_16x16x32_bf16(a0, Bf[ntl][kt], acc[0][ntl], 0, 0, 0);
            acc[1][ntl] = __builtin_amdgcn_mfma_f32_16x16x32_bf16(a1, Bf[ntl][kt], acc[1][ntl], 0, 0, 0);
        }
    }

    // store: row m = mt*16 + g*4 + r, col n = 64w + ntl*16 + c. Scalar bf16
    // stores; L2 write-combines (full tile lines filled before evict).
    #pragma unroll
    for (int mt = 0; mt < 2; ++mt)
        #pragma unroll
        for (int ntl = 0; ntl < 4; ++ntl)
            #pragma unroll
            for (int r = 0; r < 4; ++r) {
                const int m = mt * 16 + g * 4 + r;
                const int n = 64 * w + ntl * 16 + c;
                P[(size_t)(R0 + m) * HIDDEN + n] = f2bf(acc[mt][ntl][r]);
            }
}

// ---------------------------------------------------------------------------
// R4 NEW PATH, kernel B: pure gather+VALU scorer. Per pair (b,neg): read
// P[tail] (512 B bf16, mostly L3-resident), t = P+rel_part[b], normalize,
// L1 vs h_n[b]. No MFMA, no LDS tile, no barriers. Block = (b, 128 negs);
// wave = 32 pairs, software-pipelined 8 deep (static slot index, rule #20).
// ---------------------------------------------------------------------------
__global__ __launch_bounds__(256) void score2_kernel(
    const int* __restrict__ tail, const short* __restrict__ P,
    const float* __restrict__ h_n, const float* __restrict__ rel_part,
    float* __restrict__ out)
{
    const int t = threadIdx.x;
    const int w = t >> 6;
    const int l = t & 63;
    const int b = blockIdx.x >> 3;
    const int chunk = blockIdx.x & 7;
    const int base = b * NEG + chunk * CHUNK;

    __shared__ int tl[CHUNK];
    if (t < CHUNK) tl[t] = tail[base + t];

    // lane l holds dims 4l..4l+3
    const float4 hh = *reinterpret_cast<const float4*>(h_n + b * HIDDEN + 4 * l);
    const float4 rp = *reinterpret_cast<const float4*>(rel_part + b * HIDDEN + 4 * l);
    __syncthreads();

    uint2 st2[8];
    #pragma unroll
    for (int i = 0; i < 8; ++i)
        st2[i] = *(reinterpret_cast<const uint2*>(P + (size_t)tl[w * 32 + i] * HIDDEN) + l);

    #pragma unroll
    for (int p = 0; p < 32; ++p) {
        uint2 v = st2[p & 7];
        if (p + 8 < 32)   // refill same slot: p compile-time const -> static index
            st2[p & 7] = *(reinterpret_cast<const uint2*>(
                P + (size_t)tl[w * 32 + p + 8] * HIDDEN) + l);

        float t0 = __uint_as_float(v.x << 16)          + rp.x;
        float t1 = __uint_as_float(v.x & 0xffff0000u)  + rp.y;
        float t2 = __uint_as_float(v.y << 16)          + rp.z;
        float t3 = __uint_as_float(v.y & 0xffff0000u)  + rp.w;

        float ssq = t0 * t0 + t1 * t1 + t2 * t2 + t3 * t3;
        #pragma unroll
        for (int mask = 1; mask < 64; mask <<= 1) ssq += __shfl_xor(ssq, mask);
        const float rn = 1.f / fmaxf(sqrtf(ssq), 1e-12f);

        float l1 = fabsf(hh.x - t0 * rn) + fabsf(hh.y - t1 * rn)
                 + fabsf(hh.z - t2 * rn) + fabsf(hh.w - t3 * rn);
        #pragma unroll
        for (int mask = 1; mask < 64; mask <<= 1) l1 += __shfl_xor(l1, mask);

        if (l == 0) out[base + w * 32 + p] = GAMMA_F - l1;
    }
}

// ---------------------------------------------------------------------------
// FALLBACK (ws too small): R3 fused gather-GEMM score kernel, unchanged.
// ---------------------------------------------------------------------------
__global__ __launch_bounds__(256, 2) void score_kernel(
    const int* __restrict__ tail, const float* __restrict__ entity_emb,
    const short* __restrict__ W1bf, const float* __restrict__ h_n,
    const float* __restrict__ rel_part, float* __restrict__ out)
{
    __shared__ __align__(16) float Asf[2][BM * HIDDEN];
    __shared__ int tails[NTILES * BM];
    __shared__ float ssq_lds[4][BM];
    __shared__ float l1_lds[4][BM];

    const int t = threadIdx.x;
    const int w = t >> 6;
    const int l = t & 63;
    const int c = t & 15;
    const int g = (t >> 4) & 3;
    const int b = blockIdx.x >> 2;

    tails[t] = tail[blockIdx.x * (NTILES * BM) + t];

    float rlv[4], hnv[4];
    #pragma unroll
    for (int ntl = 0; ntl < 4; ++ntl) {
        const int n = 64 * w + ntl * 16 + c;
        rlv[ntl] = rel_part[b * HIDDEN + n];
        hnv[ntl] = h_n[b * HIDDEN + n];
    }

    v8s Bf[4][8];
    #pragma unroll
    for (int ntl = 0; ntl < 4; ++ntl) {
        const short* bsrc = W1bf + (size_t)(64 * w + ntl * 16 + c) * HIDDEN + g * 8;
        #pragma unroll
        for (int kt = 0; kt < 8; ++kt)
            Bf[ntl][kt] = *reinterpret_cast<const v8s*>(bsrc + kt * 32);
    }

    __syncthreads();

    v4f st[8];
    auto issue = [&](int j) {
        #pragma unroll
        for (int i = 0; i < 8; ++i) {
            const int r = w * 8 + i;
            const float* src = entity_emb + (size_t)tails[j * BM + r] * HIDDEN + (l << 2);
            st[i] = *reinterpret_cast<const v4f*>(src);
        }
        __builtin_amdgcn_sched_barrier(0);
    };
    auto commit = [&](int buf) {
        #pragma unroll
        for (int i = 0; i < 8; ++i) {
            const int r = w * 8 + i;
            *reinterpret_cast<v4f*>(&Asf[buf][r * HIDDEN + ((l ^ (r & 7)) << 2)]) = st[i];
        }
    };

    issue(0);
    commit(0);
    LDS_BARRIER();

    #pragma unroll 1
    for (int j = 0; j < NTILES; ++j) {
        const int cur = j & 1;
        if (j + 1 < NTILES) issue(j + 1);

        v4f acc[2][4];
        #pragma unroll
        for (int mt = 0; mt < 2; ++mt)
            #pragma unroll
            for (int ntl = 0; ntl < 4; ++ntl)
                acc[mt][ntl] = v4f{0.f, 0.f, 0.f, 0.f};

        const float* a0base = &Asf[cur][c * HIDDEN];
        const float* a1base = &Asf[cur][(16 + c) * HIDDEN];
        const int swz = c & 7;

        #pragma unroll
        for (int kt = 0; kt < 8; ++kt) {
            const int u0 = kt * 8 + g * 2;
            float4 x0 = *reinterpret_cast<const float4*>(a0base + (((u0    ) ^ swz) << 2));
            float4 x1 = *reinterpret_cast<const float4*>(a0base + (((u0 + 1) ^ swz) << 2));
            float4 y0 = *reinterpret_cast<const float4*>(a1base + (((u0    ) ^ swz) << 2));
            float4 y1 = *reinterpret_cast<const float4*>(a1base + (((u0 + 1) ^ swz) << 2));
            v8s a0 = pack8(x0, x1);
            v8s a1 = pack8(y0, y1);
            #pragma unroll
            for (int ntl = 0; ntl < 4; ++ntl) {
                acc[0][ntl] = __builtin_amdgcn_mfma_f32_16x16x32_bf16(a0, Bf[ntl][kt], acc[0][ntl], 0, 0, 0);
                acc[1][ntl] = __builtin_amdgcn_mfma_f32_16x16x32_bf16(a1, Bf[ntl][kt], acc[1][ntl], 0, 0, 0);
            }
        }

        #pragma unroll
        for (int mt = 0; mt < 2; ++mt) {
            float ssq[4] = {0.f, 0.f, 0.f, 0.f};
            #pragma unroll
            for (int ntl = 0; ntl < 4; ++ntl) {
                #pragma unroll
                for (int r = 0; r < 4; ++r) {
                    float tf = acc[mt][ntl][r] + rlv[ntl];
                    acc[mt][ntl][r] = tf;
                    ssq[r] += tf * tf;
                }
            }
            #pragma unroll
            for (int mask = 1; mask < 16; mask <<= 1) {
                #pragma unroll
                for (int r = 0; r < 4; ++r) ssq[r] += __shfl_xor(ssq[r], mask);
            }
            if (c == 0) {
                #pragma unroll
                for (int r = 0; r < 4; ++r) ssq_lds[w][mt * 16 + g * 4 + r] = ssq[r];
            }
        }
        LDS_BARRIER();

        #pragma unroll
        for (int mt = 0; mt < 2; ++mt) {
            float rn[4], s1[4] = {0.f, 0.f, 0.f, 0.f};
            #pragma unroll
            for (int r = 0; r < 4; ++r) {
                const int m = mt * 16 + g * 4 + r;
                float tot = ssq_lds[0][m] + ssq_lds[1][m] + ssq_lds[2][m] + ssq_lds[3][m];
                rn[r] = 1.f / fmaxf(sqrtf(tot), 1e-12f);
            }
            #pragma unroll
            for (int ntl = 0; ntl < 4; ++ntl) {
                #pragma unroll
                for (int r = 0; r < 4; ++r)
                    s1[r] += fabsf(hnv[ntl] - acc[mt][ntl][r] * rn[r]);
            }
            #pragma unroll
            for (int mask = 1; mask < 16; mask <<= 1) {
                #pragma unroll
                for (int r = 0; r < 4; ++r) s1[r] += __shfl_xor(s1[r], mask);
            }
            if (c == 0) {
                #pragma unroll
                for (int r = 0; r < 4; ++r) l1_lds[w][mt * 16 + g * 4 + r] = s1[r];
            }
        }

        if (j + 1 < NTILES) commit(cur ^ 1);
        LDS_BARRIER();

        if (t < BM) {
            out[blockIdx.x * (NTILES * BM) + j * BM + t] = GAMMA_F -
                (l1_lds[0][t] + l1_lds[1][t] + l1_lds[2][t] + l1_lds[3][t]);
        }
    }
}

extern "C" void kernel_launch(void* const* d_in, const int* in_sizes, int n_in,
                              void* d_out, int out_size, void* d_ws, size_t ws_size,
                              hipStream_t stream)
{
    const int*   head         = (const int*)d_in[0];
    const int*   tail         = (const int*)d_in[1];
    const int*   relation     = (const int*)d_in[2];
    const float* entity_emb   = (const float*)d_in[3];
    const float* relation_emb = (const float*)d_in[4];
    const float* W_fc         = (const float*)d_in[5];
    const float* b_fc         = (const float*)d_in[6];
    float* out = (float*)d_out;

    // ws layout: W1 bf16 (128 KiB) | h_n f32 (256 KiB) | rel_part f32 (256 KiB)
    //            | @1 MiB: P bf16 [200000 x 256] (102.4 MB, new path only)
    short* W1bf     = (short*)d_ws;
    float* h_n      = (float*)((char*)d_ws + 131072);
    float* rel_part = (float*)((char*)d_ws + 131072 + 262144);

    prep_kernel<<<NBATCH, 256, 0, stream>>>(head, relation, entity_emb, relation_emb,
                                            W_fc, b_fc, W1bf, h_n, rel_part);

    const size_t P_OFF   = 1ull << 20;
    const size_t P_BYTES = (size_t)NENTITY * HIDDEN * sizeof(short);  // 102,400,000
    if (ws_size >= P_OFF + P_BYTES) {
        short* P = (short*)((char*)d_ws + P_OFF);
        proj_kernel<<<NENTITY / BM, 256, 0, stream>>>(entity_emb, W1bf, P);
        score2_kernel<<<NBATCH * 8, 256, 0, stream>>>(tail, P, h_n, rel_part, out);
    } else {
        score_kernel<<<NBLK, 256, 0, stream>>>(tail, entity_emb, W1bf,
                                               h_n, rel_part, out);
    }
}

// Round 6
// 390.534 us; speedup vs baseline: 1.0575x; 1.0575x over previous
//
#include <hip/hip_runtime.h>
#include <math.h>

#define NENTITY 200000
#define HIDDEN 256
#define NEG 1024
#define NBATCH 256
#define GAMMA_F 12.0f
#define BM 32          // rows per tile
#define NTILES 8       // tiles per block (fallback path)
#define NBLK 1024      // (NBATCH*NEG)/(BM*NTILES)
#define NT_P 8         // tiles per proj block
#define CHUNK 128      // negs per score2 block

typedef short v8s __attribute__((ext_vector_type(8)));
typedef float v4f __attribute__((ext_vector_type(4)));
typedef unsigned int u32;

// raw barrier: wait LDS ops only, do NOT drain vmcnt (keeps prefetch in flight)
#define LDS_BARRIER() asm volatile("s_waitcnt lgkmcnt(0)\n\ts_barrier" ::: "memory")

// fp32 -> bf16 round-to-nearest-even
__device__ __forceinline__ short f2bf(float x) {
    u32 u = __float_as_uint(x);
    u = (u + 0x7fffu + ((u >> 16) & 1u)) >> 16;
    return (short)u;
}

// pack 8 fp32 -> v8s bf16 (round-half-up + v_perm byte-pack, 12 VALU)
__device__ __forceinline__ u32 rhu(float f) { return __float_as_uint(f) + 0x8000u; }
__device__ __forceinline__ v8s pack8(const float4& x0, const float4& x1) {
    int4 fr;
    fr.x = __builtin_amdgcn_perm(rhu(x0.y), rhu(x0.x), 0x07060302u);
    fr.y = __builtin_amdgcn_perm(rhu(x0.w), rhu(x0.z), 0x07060302u);
    fr.z = __builtin_amdgcn_perm(rhu(x1.y), rhu(x1.x), 0x07060302u);
    fr.w = __builtin_amdgcn_perm(rhu(x1.w), rhu(x1.z), 0x07060302u);
    return __builtin_bit_cast(v8s, fr);
}

// One block per batch row b: h_n[b,:], rel_part[b,:] in fp32; convert W1 row b -> bf16.
__global__ __launch_bounds__(256) void prep_kernel(
    const int* __restrict__ head, const int* __restrict__ relation,
    const float* __restrict__ entity_emb, const float* __restrict__ relation_emb,
    const float* __restrict__ W_fc, const float* __restrict__ b_fc,
    short* __restrict__ W1bf, float* __restrict__ h_n, float* __restrict__ rel_part)
{
    const int b = blockIdx.x;
    const int t = threadIdx.x;

    W1bf[b * HIDDEN + t] = f2bf(W_fc[(size_t)b * 2 * HIDDEN + t]);

    __shared__ float xh[2 * HIDDEN];
    __shared__ float xt[HIDDEN];
    __shared__ float red[256];

    const int hidx = head[b];
    const int r = relation[b];
    xh[t]          = entity_emb[(size_t)hidx * HIDDEN + t];
    xh[HIDDEN + t] = relation_emb[(size_t)r * 2 * HIDDEN + t];
    xt[t]          = relation_emb[(size_t)r * 2 * HIDDEN + HIDDEN + t];
    __syncthreads();

    const float4* wrow = reinterpret_cast<const float4*>(W_fc + (size_t)t * 2 * HIDDEN);
    float hf = b_fc[t];
    float rp = b_fc[t];
    #pragma unroll 4
    for (int kk = 0; kk < HIDDEN / 4; ++kk) {
        float4 w = wrow[kk];
        hf += xh[4*kk+0]*w.x + xh[4*kk+1]*w.y + xh[4*kk+2]*w.z + xh[4*kk+3]*w.w;
    }
    #pragma unroll 4
    for (int kk = 0; kk < HIDDEN / 4; ++kk) {
        float4 w = wrow[HIDDEN/4 + kk];
        hf += xh[HIDDEN+4*kk+0]*w.x + xh[HIDDEN+4*kk+1]*w.y + xh[HIDDEN+4*kk+2]*w.z + xh[HIDDEN+4*kk+3]*w.w;
        rp += xt[4*kk+0]*w.x + xt[4*kk+1]*w.y + xt[4*kk+2]*w.z + xt[4*kk+3]*w.w;
    }
    rel_part[b * HIDDEN + t] = rp;

    red[t] = hf * hf;
    __syncthreads();
    for (int s = 128; s > 0; s >>= 1) {
        if (t < s) red[t] += red[t + s];
        __syncthreads();
    }
    const float norm = sqrtf(red[0]);
    h_n[b * HIDDEN + t] = hf / fmaxf(norm, 1e-12f);
}

// ---------------------------------------------------------------------------
// R5 proj v2 (resubmitted R6 after infra failure): P = entity_emb @ W1^T
// (bf16) with the PROVEN pipelined block structure. R4's proj was 6250
// single-tile serial blocks (latency-bound: MfmaUtil 7%, 1.4 TB/s). Now:
// 782 blocks x 8 tiles, double-buffered LDS, issue-early/commit-late, Wf
// preloaded once per block (6250x -> 782x W1 re-reads). MFMA operands
// SWAPPED vs the score kernel: D = W_frag * E_frag puts col(lane&15)=entity,
// row=feature -> each lane owns 4 CONSECUTIVE features (reg index) of one
// entity -> in-lane v_perm bf16 pack + aligned 8B dwordx2 stores (full 32B
// sectors), no LDS transpose staging.
// ---------------------------------------------------------------------------
__global__ __launch_bounds__(256, 2) void proj_kernel(
    const float* __restrict__ entity_emb, const short* __restrict__ W1bf,
    short* __restrict__ P)
{
    __shared__ __align__(16) float Asf[2][BM * HIDDEN];  // 2 x 32 KiB

    const int t = threadIdx.x;
    const int w = t >> 6;
    const int l = t & 63;
    const int c = t & 15;
    const int g = (t >> 4) & 3;
    const int E0 = blockIdx.x * (NT_P * BM);

    // preload W fragments (A-operand): lane (c,g) holds W row 64w+f*16+c,
    // k = kt*32 + g*8 .. +8  — same fragment map as the score kernel's Bf.
    v8s Wf[4][8];
    #pragma unroll
    for (int f = 0; f < 4; ++f) {
        const short* bsrc = W1bf + (size_t)(64 * w + f * 16 + c) * HIDDEN + g * 8;
        #pragma unroll
        for (int kt = 0; kt < 8; ++kt)
            Wf[f][kt] = *reinterpret_cast<const v8s*>(bsrc + kt * 32);
    }
    #pragma unroll
    for (int f = 0; f < 4; ++f)
        #pragma unroll
        for (int kt = 0; kt < 8; ++kt)
            asm volatile("" : "+v"(Wf[f][kt]));

    // contiguous staging, 8 rows/wave/tile; loads clamped for the tail block.
    v4f st[8];
    auto issue = [&](int j) {
        #pragma unroll
        for (int i = 0; i < 8; ++i) {
            int row = E0 + j * BM + w * 8 + i;
            row = row < NENTITY ? row : NENTITY - 1;
            st[i] = *reinterpret_cast<const v4f*>(
                entity_emb + (size_t)row * HIDDEN + (l << 2));
        }
        __builtin_amdgcn_sched_barrier(0);
    };
    auto commit = [&](int buf) {
        #pragma unroll
        for (int i = 0; i < 8; ++i) {
            const int r = w * 8 + i;
            *reinterpret_cast<v4f*>(&Asf[buf][r * HIDDEN + ((l ^ (r & 7)) << 2)]) = st[i];
        }
    };

    issue(0);
    commit(0);
    LDS_BARRIER();

    #pragma unroll 1
    for (int j = 0; j < NT_P; ++j) {
        const int cur = j & 1;
        if (j + 1 < NT_P) issue(j + 1);

        v4f acc[4][2];
        #pragma unroll
        for (int f = 0; f < 4; ++f)
            #pragma unroll
            for (int et = 0; et < 2; ++et)
                acc[f][et] = v4f{0.f, 0.f, 0.f, 0.f};

        const float* a0base = &Asf[cur][c * HIDDEN];          // entities c (et=0)
        const float* a1base = &Asf[cur][(16 + c) * HIDDEN];   // entities 16+c (et=1)
        const int swz = c & 7;

        #pragma unroll
        for (int kt = 0; kt < 8; ++kt) {
            const int u0 = kt * 8 + g * 2;
            float4 x0 = *reinterpret_cast<const float4*>(a0base + (((u0    ) ^ swz) << 2));
            float4 x1 = *reinterpret_cast<const float4*>(a0base + (((u0 + 1) ^ swz) << 2));
            float4 y0 = *reinterpret_cast<const float4*>(a1base + (((u0    ) ^ swz) << 2));
            float4 y1 = *reinterpret_cast<const float4*>(a1base + (((u0 + 1) ^ swz) << 2));
            v8s e0 = pack8(x0, x1);
            v8s e1 = pack8(y0, y1);
            #pragma unroll
            for (int f = 0; f < 4; ++f) {
                acc[f][0] = __builtin_amdgcn_mfma_f32_16x16x32_bf16(Wf[f][kt], e0, acc[f][0], 0, 0, 0);
                acc[f][1] = __builtin_amdgcn_mfma_f32_16x16x32_bf16(Wf[f][kt], e1, acc[f][1], 0, 0, 0);
            }
        }

        if (j + 1 < NT_P) commit(cur ^ 1);   // ds_write other buffer (readers
                                             // of it finished in iter j-1,
                                             // gated by last iter's barrier)

        // stores: entity e = E0 + j*32 + et*16 + c; features 64w+f*16+g*4+{0..3}
        // packed to 2 bf16-pairs in-lane -> 8B aligned dwordx2.
        #pragma unroll
        for (int et = 0; et < 2; ++et) {
            const int e = E0 + j * BM + et * 16 + c;
            if (e < NENTITY) {
                short* dst = P + (size_t)e * HIDDEN + 64 * w + g * 4;
                #pragma unroll
                for (int f = 0; f < 4; ++f) {
                    uint2 pk;
                    pk.x = __builtin_amdgcn_perm(rhu(acc[f][et][1]), rhu(acc[f][et][0]), 0x07060302u);
                    pk.y = __builtin_amdgcn_perm(rhu(acc[f][et][3]), rhu(acc[f][et][2]), 0x07060302u);
                    *reinterpret_cast<uint2*>(dst + f * 16) = pk;
                }
            }
        }

        LDS_BARRIER();   // commit visible; next iter may read cur^1
    }
}

// ---------------------------------------------------------------------------
// score2: pure gather+VALU scorer (R4-proven, ~46 us). Per pair (b,neg):
// read P[tail] (512 B bf16, L3-resident), t = P+rel_part[b], normalize,
// L1 vs h_n[b]. No MFMA, no LDS tile, no barriers.
// ---------------------------------------------------------------------------
__global__ __launch_bounds__(256) void score2_kernel(
    const int* __restrict__ tail, const short* __restrict__ P,
    const float* __restrict__ h_n, const float* __restrict__ rel_part,
    float* __restrict__ out)
{
    const int t = threadIdx.x;
    const int w = t >> 6;
    const int l = t & 63;
    const int b = blockIdx.x >> 3;
    const int chunk = blockIdx.x & 7;
    const int base = b * NEG + chunk * CHUNK;

    __shared__ int tl[CHUNK];
    if (t < CHUNK) tl[t] = tail[base + t];

    // lane l holds dims 4l..4l+3
    const float4 hh = *reinterpret_cast<const float4*>(h_n + b * HIDDEN + 4 * l);
    const float4 rp = *reinterpret_cast<const float4*>(rel_part + b * HIDDEN + 4 * l);
    __syncthreads();

    uint2 st2[8];
    #pragma unroll
    for (int i = 0; i < 8; ++i)
        st2[i] = *(reinterpret_cast<const uint2*>(P + (size_t)tl[w * 32 + i] * HIDDEN) + l);

    #pragma unroll
    for (int p = 0; p < 32; ++p) {
        uint2 v = st2[p & 7];
        if (p + 8 < 32)   // refill same slot: p compile-time const -> static index
            st2[p & 7] = *(reinterpret_cast<const uint2*>(
                P + (size_t)tl[w * 32 + p + 8] * HIDDEN) + l);

        float t0 = __uint_as_float(v.x << 16)          + rp.x;
        float t1 = __uint_as_float(v.x & 0xffff0000u)  + rp.y;
        float t2 = __uint_as_float(v.y << 16)          + rp.z;
        float t3 = __uint_as_float(v.y & 0xffff0000u)  + rp.w;

        float ssq = t0 * t0 + t1 * t1 + t2 * t2 + t3 * t3;
        #pragma unroll
        for (int mask = 1; mask < 64; mask <<= 1) ssq += __shfl_xor(ssq, mask);
        const float rn = 1.f / fmaxf(sqrtf(ssq), 1e-12f);

        float l1 = fabsf(hh.x - t0 * rn) + fabsf(hh.y - t1 * rn)
                 + fabsf(hh.z - t2 * rn) + fabsf(hh.w - t3 * rn);
        #pragma unroll
        for (int mask = 1; mask < 64; mask <<= 1) l1 += __shfl_xor(l1, mask);

        if (l == 0) out[base + w * 32 + p] = GAMMA_F - l1;
    }
}

// ---------------------------------------------------------------------------
// FALLBACK (ws too small): R3 fused gather-GEMM score kernel, unchanged.
// ---------------------------------------------------------------------------
__global__ __launch_bounds__(256, 2) void score_kernel(
    const int* __restrict__ tail, const float* __restrict__ entity_emb,
    const short* __restrict__ W1bf, const float* __restrict__ h_n,
    const float* __restrict__ rel_part, float* __restrict__ out)
{
    __shared__ __align__(16) float Asf[2][BM * HIDDEN];
    __shared__ int tails[NTILES * BM];
    __shared__ float ssq_lds[4][BM];
    __shared__ float l1_lds[4][BM];

    const int t = threadIdx.x;
    const int w = t >> 6;
    const int l = t & 63;
    const int c = t & 15;
    const int g = (t >> 4) & 3;
    const int b = blockIdx.x >> 2;

    tails[t] = tail[blockIdx.x * (NTILES * BM) + t];

    float rlv[4], hnv[4];
    #pragma unroll
    for (int ntl = 0; ntl < 4; ++ntl) {
        const int n = 64 * w + ntl * 16 + c;
        rlv[ntl] = rel_part[b * HIDDEN + n];
        hnv[ntl] = h_n[b * HIDDEN + n];
    }

    v8s Bf[4][8];
    #pragma unroll
    for (int ntl = 0; ntl < 4; ++ntl) {
        const short* bsrc = W1bf + (size_t)(64 * w + ntl * 16 + c) * HIDDEN + g * 8;
        #pragma unroll
        for (int kt = 0; kt < 8; ++kt)
            Bf[ntl][kt] = *reinterpret_cast<const v8s*>(bsrc + kt * 32);
    }

    __syncthreads();

    v4f st[8];
    auto issue = [&](int j) {
        #pragma unroll
        for (int i = 0; i < 8; ++i) {
            const int r = w * 8 + i;
            const float* src = entity_emb + (size_t)tails[j * BM + r] * HIDDEN + (l << 2);
            st[i] = *reinterpret_cast<const v4f*>(src);
        }
        __builtin_amdgcn_sched_barrier(0);
    };
    auto commit = [&](int buf) {
        #pragma unroll
        for (int i = 0; i < 8; ++i) {
            const int r = w * 8 + i;
            *reinterpret_cast<v4f*>(&Asf[buf][r * HIDDEN + ((l ^ (r & 7)) << 2)]) = st[i];
        }
    };

    issue(0);
    commit(0);
    LDS_BARRIER();

    #pragma unroll 1
    for (int j = 0; j < NTILES; ++j) {
        const int cur = j & 1;
        if (j + 1 < NTILES) issue(j + 1);

        v4f acc[2][4];
        #pragma unroll
        for (int mt = 0; mt < 2; ++mt)
            #pragma unroll
            for (int ntl = 0; ntl < 4; ++ntl)
                acc[mt][ntl] = v4f{0.f, 0.f, 0.f, 0.f};

        const float* a0base = &Asf[cur][c * HIDDEN];
        const float* a1base = &Asf[cur][(16 + c) * HIDDEN];
        const int swz = c & 7;

        #pragma unroll
        for (int kt = 0; kt < 8; ++kt) {
            const int u0 = kt * 8 + g * 2;
            float4 x0 = *reinterpret_cast<const float4*>(a0base + (((u0    ) ^ swz) << 2));
            float4 x1 = *reinterpret_cast<const float4*>(a0base + (((u0 + 1) ^ swz) << 2));
            float4 y0 = *reinterpret_cast<const float4*>(a1base + (((u0    ) ^ swz) << 2));
            float4 y1 = *reinterpret_cast<const float4*>(a1base + (((u0 + 1) ^ swz) << 2));
            v8s a0 = pack8(x0, x1);
            v8s a1 = pack8(y0, y1);
            #pragma unroll
            for (int ntl = 0; ntl < 4; ++ntl) {
                acc[0][ntl] = __builtin_amdgcn_mfma_f32_16x16x32_bf16(a0, Bf[ntl][kt], acc[0][ntl], 0, 0, 0);
                acc[1][ntl] = __builtin_amdgcn_mfma_f32_16x16x32_bf16(a1, Bf[ntl][kt], acc[1][ntl], 0, 0, 0);
            }
        }

        #pragma unroll
        for (int mt = 0; mt < 2; ++mt) {
            float ssq[4] = {0.f, 0.f, 0.f, 0.f};
            #pragma unroll
            for (int ntl = 0; ntl < 4; ++ntl) {
                #pragma unroll
                for (int r = 0; r < 4; ++r) {
                    float tf = acc[mt][ntl][r] + rlv[ntl];
                    acc[mt][ntl][r] = tf;
                    ssq[r] += tf * tf;
                }
            }
            #pragma unroll
            for (int mask = 1; mask < 16; mask <<= 1) {
                #pragma unroll
                for (int r = 0; r < 4; ++r) ssq[r] += __shfl_xor(ssq[r], mask);
            }
            if (c == 0) {
                #pragma unroll
                for (int r = 0; r < 4; ++r) ssq_lds[w][mt * 16 + g * 4 + r] = ssq[r];
            }
        }
        LDS_BARRIER();

        #pragma unroll
        for (int mt = 0; mt < 2; ++mt) {
            float rn[4], s1[4] = {0.f, 0.f, 0.f, 0.f};
            #pragma unroll
            for (int r = 0; r < 4; ++r) {
                const int m = mt * 16 + g * 4 + r;
                float tot = ssq_lds[0][m] + ssq_lds[1][m] + ssq_lds[2][m] + ssq_lds[3][m];
                rn[r] = 1.f / fmaxf(sqrtf(tot), 1e-12f);
            }
            #pragma unroll
            for (int ntl = 0; ntl < 4; ++ntl) {
                #pragma unroll
                for (int r = 0; r < 4; ++r)
                    s1[r] += fabsf(hnv[ntl] - acc[mt][ntl][r] * rn[r]);
            }
            #pragma unroll
            for (int mask = 1; mask < 16; mask <<= 1) {
                #pragma unroll
                for (int r = 0; r < 4; ++r) s1[r] += __shfl_xor(s1[r], mask);
            }
            if (c == 0) {
                #pragma unroll
                for (int r = 0; r < 4; ++r) l1_lds[w][mt * 16 + g * 4 + r] = s1[r];
            }
        }

        if (j + 1 < NTILES) commit(cur ^ 1);
        LDS_BARRIER();

        if (t < BM) {
            out[blockIdx.x * (NTILES * BM) + j * BM + t] = GAMMA_F -
                (l1_lds[0][t] + l1_lds[1][t] + l1_lds[2][t] + l1_lds[3][t]);
        }
    }
}

extern "C" void kernel_launch(void* const* d_in, const int* in_sizes, int n_in,
                              void* d_out, int out_size, void* d_ws, size_t ws_size,
                              hipStream_t stream)
{
    const int*   head         = (const int*)d_in[0];
    const int*   tail         = (const int*)d_in[1];
    const int*   relation     = (const int*)d_in[2];
    const float* entity_emb   = (const float*)d_in[3];
    const float* relation_emb = (const float*)d_in[4];
    const float* W_fc         = (const float*)d_in[5];
    const float* b_fc         = (const float*)d_in[6];
    float* out = (float*)d_out;

    // ws layout: W1 bf16 (128 KiB) | h_n f32 (256 KiB) | rel_part f32 (256 KiB)
    //            | @1 MiB: P bf16 [200000 x 256] (102.4 MB, new path only)
    short* W1bf     = (short*)d_ws;
    float* h_n      = (float*)((char*)d_ws + 131072);
    float* rel_part = (float*)((char*)d_ws + 131072 + 262144);

    prep_kernel<<<NBATCH, 256, 0, stream>>>(head, relation, entity_emb, relation_emb,
                                            W_fc, b_fc, W1bf, h_n, rel_part);

    const size_t P_OFF   = 1ull << 20;
    const size_t P_BYTES = (size_t)NENTITY * HIDDEN * sizeof(short);  // 102,400,000
    if (ws_size >= P_OFF + P_BYTES) {
        short* P = (short*)((char*)d_ws + P_OFF);
        const int grid = (NENTITY + NT_P * BM - 1) / (NT_P * BM);   // 782
        proj_kernel<<<grid, 256, 0, stream>>>(entity_emb, W1bf, P);
        score2_kernel<<<NBATCH * 8, 256, 0, stream>>>(tail, P, h_n, rel_part, out);
    } else {
        score_kernel<<<NBLK, 256, 0, stream>>>(tail, entity_emb, W1bf,
                                               h_n, rel_part, out);
    }
}